// Round 6
// baseline (76.313 us; speedup 1.0000x reference)
//
#include <hip/hip_runtime.h>
#include <hip/hip_bf16.h>

#define BS 32
#define NQ 300
#define NC 92
#define NT 50
#define Q_TOT (BS * NQ)   // 9600
#define T_TOT (BS * NT)   // 1600
#define QPB 8             // q-rows per block (9600 = 1200 * 8)
#define TPB 320           // threads per block = targets per block
#define SLAB ((size_t)Q_TOT * (size_t)T_TOT)   // floats per output replica

// K1: per-query softmax stats (rowmax, 1/sumexp) — one wave64 per row.
__global__ __launch_bounds__(256) void softmax_stats_kernel(
    const float* __restrict__ logits,   // [Q_TOT, NC]
    float2* __restrict__ stats)         // [Q_TOT]
{
    const int row  = blockIdx.x * 4 + (threadIdx.x >> 6);
    const int lane = threadIdx.x & 63;

    const float* rp = logits + (size_t)row * NC;
    float x0 = (lane < NC)      ? rp[lane]      : -INFINITY;
    float x1 = (lane + 64 < NC) ? rp[lane + 64] : -INFINITY;

    float m = fmaxf(x0, x1);
    #pragma unroll
    for (int off = 1; off < 64; off <<= 1)
        m = fmaxf(m, __shfl_xor(m, off));

    float s = __expf(x0 - m) + __expf(x1 - m);   // exp(-inf - m) == 0
    #pragma unroll
    for (int off = 1; off < 64; off <<= 1)
        s += __shfl_xor(s, off);

    if (lane == 0)
        stats[row] = make_float2(m, 1.0f / s);
}

// K2: R1 structure (thread = target, loop over 8 q-rows).
// DIAGNOSTIC: gridDim.z replicas compute identical full work; z=0 writes the
// real output, z>0 write to distinct d_ws slabs (honest extra write streams).
__global__ __launch_bounds__(TPB) void cost_kernel(
    const float* __restrict__ pred_logits,  // [Q_TOT, NC]
    const float* __restrict__ pred_boxes,   // [Q_TOT, 4] cxcywh
    const int*   __restrict__ tgt_labels,   // [T_TOT]
    const float* __restrict__ tgt_boxes,    // [T_TOT, 4] cxcywh
    const float2* __restrict__ stats,       // [Q_TOT]
    float* __restrict__ out,                // [Q_TOT, T_TOT]
    float* __restrict__ ws_rep)             // replica slabs
{
    float* dst = (blockIdx.z == 0) ? out
               : ws_rep + (size_t)(blockIdx.z - 1) * SLAB;

    const int t  = blockIdx.x * TPB + threadIdx.x;
    const int q0 = blockIdx.y * QPB;

    const float4 tb = *reinterpret_cast<const float4*>(tgt_boxes + 4 * t);
    const float tx0 = tb.x - 0.5f * tb.z, ty0 = tb.y - 0.5f * tb.w;
    const float tx1 = tb.x + 0.5f * tb.z, ty1 = tb.y + 0.5f * tb.w;
    const float tarea = tb.z * tb.w;
    const int lbl = tgt_labels[t];

    #pragma unroll
    for (int i = 0; i < QPB; ++i) {
        const int q = q0 + i;
        const float4 qb = *reinterpret_cast<const float4*>(pred_boxes + 4 * q);
        const float2 st = stats[q];
        const float logit = pred_logits[(size_t)q * NC + lbl];
        const float prob  = __expf(logit - st.x) * st.y;

        const float l1 = fabsf(qb.x - tb.x) + fabsf(qb.y - tb.y)
                       + fabsf(qb.z - tb.z) + fabsf(qb.w - tb.w);

        const float qx0 = qb.x - 0.5f * qb.z, qy0 = qb.y - 0.5f * qb.w;
        const float qx1 = qb.x + 0.5f * qb.z, qy1 = qb.y + 0.5f * qb.w;
        const float qarea = qb.z * qb.w;

        const float ix0 = fmaxf(qx0, tx0), iy0 = fmaxf(qy0, ty0);
        const float ix1 = fminf(qx1, tx1), iy1 = fminf(qy1, ty1);
        const float iw = fmaxf(ix1 - ix0, 0.0f), ih = fmaxf(iy1 - iy0, 0.0f);
        const float inter = iw * ih;
        const float uni   = qarea + tarea - inter;

        const float ex0 = fminf(qx0, tx0), ey0 = fminf(qy0, ty0);
        const float ex1 = fmaxf(qx1, tx1), ey1 = fmaxf(qy1, ty1);
        const float earea = (ex1 - ex0) * (ey1 - ey0);

        const float ue = uni * earea;
        const float r  = __builtin_amdgcn_rcpf(ue);
        float num = inter * earea - ue;
        num = fmaf(uni, uni, num);
        const float giou = num * r;

        dst[(size_t)q * T_TOT + t] = l1 - prob - giou;
    }
}

extern "C" void kernel_launch(void* const* d_in, const int* in_sizes, int n_in,
                              void* d_out, int out_size, void* d_ws, size_t ws_size,
                              hipStream_t stream) {
    const float* pred_logits = (const float*)d_in[0]; // [32,300,92]
    const float* pred_boxes  = (const float*)d_in[1]; // [32,300,4]
    const int*   tgt_labels  = (const int*)d_in[2];   // [32,50]
    const float* tgt_boxes   = (const float*)d_in[3]; // [32,50,4]
    float* out = (float*)d_out;                       // [32,300,1600]

    // stats live at the (256B-aligned) tail of d_ws; replica slabs at the head.
    const size_t stats_rsv = ((Q_TOT * sizeof(float2)) + 255) / 256 * 256;
    float2* stats = (float2*)((char*)d_ws + (ws_size - stats_rsv));
    float* ws_rep = (float*)d_ws;

    int extra = 0;
    if (ws_size > stats_rsv) {
        extra = (int)((ws_size - stats_rsv) / (SLAB * sizeof(float)));
        if (extra > 3) extra = 3;
    }

    softmax_stats_kernel<<<Q_TOT / 4, 256, 0, stream>>>(pred_logits, stats);

    dim3 grid(T_TOT / TPB, Q_TOT / QPB, 1 + extra);   // (5, 1200, up to 4)
    cost_kernel<<<grid, TPB, 0, stream>>>(pred_logits, pred_boxes, tgt_labels,
                                          tgt_boxes, stats, out, ws_rep);
}

// Round 7
// 26.843 us; speedup vs baseline: 2.8430x; 2.8430x over previous
//
#include <hip/hip_runtime.h>
#include <hip/hip_bf16.h>

#define BS 32
#define NQ 300
#define NC 92
#define NT 50
#define Q_TOT (BS * NQ)   // 9600
#define T_TOT (BS * NT)   // 1600
#define QPB 8             // q-rows per block (9600 = 1200 * 8)
#define TPB 320           // threads per block = targets per block

typedef float f2 __attribute__((ext_vector_type(2)));

static __device__ __forceinline__ f2 fma2(f2 a, f2 b, f2 c) {
    return __builtin_elementwise_fma(a, b, c);
}
static __device__ __forceinline__ f2 max2(f2 a, f2 b) {
    return __builtin_elementwise_max(a, b);
}
static __device__ __forceinline__ f2 abs2(f2 a) {
    return __builtin_elementwise_abs(a);
}

// K1: one wave per query row. Computes softmax stats AND repacks the q-side
// into SoA tables so K2 can load (q, q+1) pairs as single 8B loads:
//   ws layout: qcx | qcy | qhw(=w/2) | qhh(=h/2) | qar | qm | qinv, each [Q_TOT]
__global__ __launch_bounds__(256) void prep_kernel(
    const float* __restrict__ logits,   // [Q_TOT, NC]
    const float* __restrict__ boxes,    // [Q_TOT, 4] cxcywh
    float* __restrict__ ws)
{
    const int row  = blockIdx.x * 4 + (threadIdx.x >> 6);
    const int lane = threadIdx.x & 63;

    const float* rp = logits + (size_t)row * NC;
    float x0 = (lane < NC)      ? rp[lane]      : -INFINITY;
    float x1 = (lane + 64 < NC) ? rp[lane + 64] : -INFINITY;

    float m = fmaxf(x0, x1);
    #pragma unroll
    for (int off = 1; off < 64; off <<= 1)
        m = fmaxf(m, __shfl_xor(m, off));

    float s = __expf(x0 - m) + __expf(x1 - m);   // exp(-inf - m) == 0
    #pragma unroll
    for (int off = 1; off < 64; off <<= 1)
        s += __shfl_xor(s, off);

    if (lane == 0) {
        const float4 b = *reinterpret_cast<const float4*>(boxes + 4 * row);
        ws[0 * Q_TOT + row] = b.x;               // qcx
        ws[1 * Q_TOT + row] = b.y;               // qcy
        ws[2 * Q_TOT + row] = 0.5f * b.z;        // qhw
        ws[3 * Q_TOT + row] = 0.5f * b.w;        // qhh
        ws[4 * Q_TOT + row] = b.z * b.w;         // qar
        ws[5 * Q_TOT + row] = m;                 // qm
        ws[6 * Q_TOT + row] = 1.0f / s;          // qinv
    }
}

// K2: thread = one target; 8 q-rows as 4 packed (q, q+1) f32-pairs.
// Per-dim identities (exact in real arithmetic):
//   dx  = (hwq+hwt) - max(|u|,|v|)   u = qcx-tcx, v = hwq-hwt   (pre-clamp inter width)
//   iw  = max(dx, 0)
//   ew  = 2*(hwq+hwt) - dx           (enclosing width, no min/max)
//   l1x = |u| + 2|v|                 (shares |u|,|v|)
__global__ __launch_bounds__(TPB) void cost_kernel_pk(
    const float* __restrict__ logits,       // [Q_TOT, NC]
    const int*   __restrict__ tgt_labels,   // [T_TOT]
    const float* __restrict__ tgt_boxes,    // [T_TOT, 4] cxcywh
    const float* __restrict__ ws,           // SoA q-tables (see K1)
    float* __restrict__ out)                // [Q_TOT, T_TOT]
{
    const float* qcx_t = ws + 0 * Q_TOT;
    const float* qcy_t = ws + 1 * Q_TOT;
    const float* qhw_t = ws + 2 * Q_TOT;
    const float* qhh_t = ws + 3 * Q_TOT;
    const float* qar_t = ws + 4 * Q_TOT;
    const float* qm_t  = ws + 5 * Q_TOT;
    const float* qiv_t = ws + 6 * Q_TOT;

    const int t  = blockIdx.x * TPB + threadIdx.x;
    const int q0 = blockIdx.y * QPB;

    // t-side, broadcast into both pk halves (hoisted once per thread)
    const float4 tb = *reinterpret_cast<const float4*>(tgt_boxes + 4 * t);
    const f2 tcx = {tb.x, tb.x};
    const f2 tcy = {tb.y, tb.y};
    const f2 thw = {0.5f * tb.z, 0.5f * tb.z};
    const f2 thh = {0.5f * tb.w, 0.5f * tb.w};
    const f2 tar = {tb.z * tb.w, tb.z * tb.w};
    const int lbl = tgt_labels[t];

    const float* lp = logits + (size_t)q0 * NC + lbl;  // per-thread gather base
    float* op = out + (size_t)q0 * T_TOT + t;
    const f2 two = {2.0f, 2.0f};
    const f2 zero = {0.0f, 0.0f};

    #pragma unroll
    for (int p = 0; p < QPB / 2; ++p) {
        const int q = q0 + 2 * p;

        // q-pair tables: single 8B loads (uniform address -> scalar loads)
        const f2 qcx = *reinterpret_cast<const f2*>(qcx_t + q);
        const f2 qcy = *reinterpret_cast<const f2*>(qcy_t + q);
        const f2 qhw = *reinterpret_cast<const f2*>(qhw_t + q);
        const f2 qhh = *reinterpret_cast<const f2*>(qhh_t + q);
        const f2 qar = *reinterpret_cast<const f2*>(qar_t + q);
        const f2 qm  = *reinterpret_cast<const f2*>(qm_t  + q);
        const f2 qiv = *reinterpret_cast<const f2*>(qiv_t + q);

        // class cost: 2 divergent gathers, compile-time offsets off one base
        const f2 lg = {lp[184 * p], lp[184 * p + NC]};

        const f2 ux = qcx - tcx,  uy = qcy - tcy;     // pk_sub
        const f2 vx = qhw - thw,  vy = qhh - thh;     // pk_sub
        const f2 hx = qhw + thw,  hy = qhh + thh;     // pk_add
        const f2 aux = abs2(ux), auy = abs2(uy);      // v_and x2 each
        const f2 avx = abs2(vx), avy = abs2(vy);
        const f2 mx = max2(aux, avx), my = max2(auy, avy);  // scalar max x2
        const f2 dx = hx - mx, dy = hy - my;          // pk_sub
        const f2 iw = max2(dx, zero), ih = max2(dy, zero);
        const f2 ew = fma2(two, hx, -dx);             // enclosing w = 2hs - dx
        const f2 eh = fma2(two, hy, -dy);

        const f2 inter = iw * ih;
        const f2 earea = ew * eh;
        const f2 uni   = (qar + tar) - inter;
        const f2 ue    = uni * earea;
        const f2 rc    = {__builtin_amdgcn_rcpf(ue.x), __builtin_amdgcn_rcpf(ue.y)};
        // giou = (inter*earea - ue + uni^2) * rcp(ue)
        const f2 giou  = fma2(uni, uni, inter * earea - ue) * rc;

        // l1 = |ux|+2|vx| + |uy|+2|vy|
        const f2 l1 = fma2(two, avx, aux) + fma2(two, avy, auy);

        // prob = exp(lg - m) * inv
        const f2 pe = lg - qm;
        f2 prob = {__expf(pe.x), __expf(pe.y)};
        prob *= qiv;

        const f2 res = l1 - prob - giou;
        op[3200 * p]        = res.x;   // row q   (coalesced along t)
        op[3200 * p + 1600] = res.y;   // row q+1
    }
}

extern "C" void kernel_launch(void* const* d_in, const int* in_sizes, int n_in,
                              void* d_out, int out_size, void* d_ws, size_t ws_size,
                              hipStream_t stream) {
    const float* pred_logits = (const float*)d_in[0]; // [32,300,92]
    const float* pred_boxes  = (const float*)d_in[1]; // [32,300,4]
    const int*   tgt_labels  = (const int*)d_in[2];   // [32,50]
    const float* tgt_boxes   = (const float*)d_in[3]; // [32,50,4]
    float* out = (float*)d_out;                       // [32,300,1600]
    float* ws  = (float*)d_ws;                        // 7 * 9600 f32 = 262.5 KB

    prep_kernel<<<Q_TOT / 4, 256, 0, stream>>>(pred_logits, pred_boxes, ws);

    dim3 grid(T_TOT / TPB, Q_TOT / QPB);              // (5, 1200)
    cost_kernel_pk<<<grid, TPB, 0, stream>>>(pred_logits, tgt_labels,
                                             tgt_boxes, ws, out);
}